// Round 1
// baseline (4854.075 us; speedup 1.0000x reference)
//
#include <hip/hip_runtime.h>
#include <math.h>

#define HD 128
#define LW 32
#define VOCABN 200000
#define NLEAF 2048
#define NPAR 2047
#define NNODE 4095
#define MAXC 4
#define NCLASS 4
#define SCALE 0.08838834764831845f  // 1/sqrt(128)

// Workspace layout (floats), compile-time offsets => k_seq needs ONE base ptr
#define OFF_XE   0
#define OFF_NODE 524160    // + NNODE*HD
#define OFF_W3   786304    // + NLEAF*HD
#define OFF_WQ   851840    // + 512*HD
#define OFF_AZ   1113856   // + NPAR*HD
#define OFF_AR   1375872
#define OFF_AH   1637888
#define OFF_PREV 1899904
#define OFF_ES   2685952   // + NPAR*384
#define OFF_HG   2688000   // (unused by k_seq now; layout kept stable)
#define OFF_HTR  2688128
#define OFF_ET   2688256
#define WS_END   (OFF_ET + (size_t)VOCABN * HD)

// LDS-only barrier: lgkmcnt(0) makes ds_writes visible, does NOT drain vmcnt
// (prefetch global loads stay in flight across it).
#define BARL() asm volatile("s_waitcnt lgkmcnt(0)\n\ts_barrier" ::: "memory")
// Pin float4 into VGPRs component-wise.
#define PIN4(v) asm volatile("" : "+v"((v).x), "+v"((v).y), "+v"((v).z), "+v"((v).w))
#define LD4(p, k) (*(const float4*)((p) + 4 * (k)))

// dot chunk: W = float4 weights, X = float4 x-values
#define CHV(W, X) { a0 += (W).x * (X).x + (W).y * (X).y; \
                    a1 += (W).z * (X).z + (W).w * (X).w; }

#define PIN_ALL() do { PIN4(A0); PIN4(A1); PIN4(A2); PIN4(A3); \
    PIN4(A4); PIN4(A5); PIN4(A6); PIN4(A7); PIN4(A8); PIN4(A9); \
    PIN4(A10); PIN4(A11); PIN4(A12); PIN4(A13); PIN4(A14); PIN4(A15); } while (0)

// ---------------------------------------------------------------------------
// Kernel 1a (fallback): xe via uncoalesced gather
// ---------------------------------------------------------------------------
__global__ void k_xe(const float* __restrict__ xw, const int* __restrict__ xi,
                     const float* __restrict__ E, float* __restrict__ xe) {
    int n = blockIdx.x;
    int h = threadIdx.x;
    __shared__ int   sidx[LW];
    __shared__ float sw[LW];
    if (h < LW) { sidx[h] = xi[n * LW + h]; sw[h] = xw[n * LW + h]; }
    __syncthreads();
    float acc = 0.f;
#pragma unroll
    for (int l = 0; l < LW; ++l)
        acc += E[(size_t)h * VOCABN + sidx[l]] * sw[l];
    xe[(size_t)n * HD + h] = acc;
}

// ---------------------------------------------------------------------------
// Kernel 1b: transpose E (H x VOCAB) -> ET (VOCAB x H)
// ---------------------------------------------------------------------------
__global__ void k_transpose(const float* __restrict__ E, float* __restrict__ ET) {
    __shared__ float tile[32][33];
    int vb = blockIdx.x * 32, hb = blockIdx.y * 32;
    int tx = threadIdx.x, ty = threadIdx.y;  // 32 x 8
#pragma unroll
    for (int r = 0; r < 32; r += 8)
        tile[ty + r][tx] = E[(size_t)(hb + ty + r) * VOCABN + vb + tx];
    __syncthreads();
#pragma unroll
    for (int r = 0; r < 32; r += 8)
        ET[(size_t)(vb + ty + r) * HD + hb + tx] = tile[tx][ty + r];
}

// Kernel 1c: coalesced gather+reduce from ET.
__global__ void k_xe_t(const float* __restrict__ xw, const int* __restrict__ xi,
                       const float* __restrict__ ET, float* __restrict__ xe) {
    int n = blockIdx.x;
    int h = threadIdx.x;
    __shared__ int   sidx[LW];
    __shared__ float sw[LW];
    if (h < LW) { sidx[h] = xi[n * LW + h]; sw[h] = xw[n * LW + h]; }
    __syncthreads();
    float acc = 0.f;
#pragma unroll
    for (int l = 0; l < LW; ++l)
        acc += ET[(size_t)sidx[l] * HD + h] * sw[l];
    xe[(size_t)n * HD + h] = acc;
}

// ---------------------------------------------------------------------------
// Kernel 2: leaf cells -> node_h[0:NLEAF]
// ---------------------------------------------------------------------------
__global__ void k_leaf(const float* __restrict__ xe, const float* __restrict__ Wz,
                       const float* __restrict__ bz, const float* __restrict__ Wh,
                       const float* __restrict__ bh, float* __restrict__ node_h) {
    int n = blockIdx.x;
    int j = threadIdx.x;
    __shared__ float xl[HD];
    xl[j] = xe[(size_t)n * HD + j];
    __syncthreads();
    float az = bz[j], ah = bh[j];
    const float* wzr = Wz + (size_t)j * HD;
    const float* whr = Wh + (size_t)j * HD;
#pragma unroll 4
    for (int k = 0; k < HD; ++k) { az += wzr[k] * xl[k]; ah += whr[k] * xl[k]; }
    float z = 1.f / (1.f + expf(-az));
    float c = tanhf(ah);
    node_h[(size_t)n * HD + j] = (1.f - z) * c;
}

// ---------------------------------------------------------------------------
// Kernel 3: fused weight stack W3 (512 x 128):
//   rows 0..127: WV^T / 128..255: U_z WV^T / 256..383: U_r WV^T / 384..511: U_h
// ---------------------------------------------------------------------------
__global__ void k_fuse(const float* __restrict__ WV, const float* __restrict__ Uz,
                       const float* __restrict__ Ur, const float* __restrict__ Uh,
                       float* __restrict__ w3) {
    int r = blockIdx.x;
    int b = threadIdx.x;
    float v;
    if (r < 128) {
        v = WV[(size_t)b * HD + r];
    } else if (r < 384) {
        const float* u  = (r < 256 ? Uz + (size_t)(r - 128) * HD : Ur + (size_t)(r - 256) * HD);
        const float* wv = WV + (size_t)b * HD;
        float a = 0.f;
#pragma unroll 4
        for (int j = 0; j < HD; ++j) a += u[j] * wv[j];
        v = a;
    } else {
        v = Uh[(size_t)(r - 384) * HD + b];
    }
    w3[(size_t)r * HD + b] = v;
}

// ---------------------------------------------------------------------------
// Kernel 4: per-parent precompute
// ---------------------------------------------------------------------------
__global__ void k_ppre(const float* __restrict__ xe, const float* __restrict__ WQ,
                       const float* __restrict__ WK, const float* __restrict__ Wz,
                       const float* __restrict__ bz, const float* __restrict__ Wr,
                       const float* __restrict__ br, const float* __restrict__ Wh,
                       const float* __restrict__ bh, float* __restrict__ wq,
                       float* __restrict__ az, float* __restrict__ ar,
                       float* __restrict__ ah) {
    int i = blockIdx.x;
    int j = threadIdx.x;
    __shared__ float xl[HD], ql[HD];
    xl[j] = xe[(size_t)(NLEAF + i) * HD + j];
    __syncthreads();
    float q = 0.f;
#pragma unroll 4
    for (int h = 0; h < HD; ++h) q += xl[h] * WQ[(size_t)h * HD + j];
    ql[j] = 1.f / (1.f + expf(-q));
    __syncthreads();
    float w = 0.f;
#pragma unroll 4
    for (int k = 0; k < HD; ++k) w += WK[(size_t)j * HD + k] * ql[k];
    wq[(size_t)i * HD + j] = w;
    float vz = bz[j], vr = br[j], vh = bh[j];
#pragma unroll 4
    for (int k = 0; k < HD; ++k) {
        float xv = xl[k];
        vz += Wz[(size_t)j * HD + k] * xv;
        vr += Wr[(size_t)j * HD + k] * xv;
        vh += Wh[(size_t)j * HD + k] * xv;
    }
    az[(size_t)i * HD + j] = vz;
    ar[(size_t)i * HD + j] = vr;
    ah[(size_t)i * HD + j] = vh;
}

// ---------------------------------------------------------------------------
// Kernel 5: aggregated leaf-child precompute per parent
// ---------------------------------------------------------------------------
__global__ void k_chpre(const int* __restrict__ tree, const float* __restrict__ node_h,
                        const float* __restrict__ w3, const float* __restrict__ wq_all,
                        float* __restrict__ preVexp, float* __restrict__ expsum) {
    int i = blockIdx.x;
    int j = threadIdx.x;
    __shared__ float hl[HD];
    __shared__ float red[HD];
    float wqj = wq_all[(size_t)i * HD + j];
    float acc0 = 0.f, acc1 = 0.f, acc2 = 0.f, esum = 0.f;
    for (int c = 0; c < MAXC; ++c) {
        int child = tree[i * MAXC + c];
        if (child < 0 || child >= NLEAF) continue;  // uniform per block
        __syncthreads();
        hl[j] = node_h[(size_t)child * HD + j];
        __syncthreads();
        red[j] = hl[j] * wqj;
        __syncthreads();
        for (int s = 64; s > 0; s >>= 1) {
            if (j < s) red[j] += red[j + s];
            __syncthreads();
        }
        float e = expf(red[0] * SCALE);
        float d0 = 0.f, d1 = 0.f, d2 = 0.f;
#pragma unroll 4
        for (int k = 0; k < HD; ++k) {
            float x = hl[k];
            d0 += w3[(size_t)j * HD + k] * x;
            d1 += w3[(size_t)(128 + j) * HD + k] * x;
            d2 += w3[(size_t)(256 + j) * HD + k] * x;
        }
        acc0 += e * d0; acc1 += e * d1; acc2 += e * d2; esum += e;
    }
    preVexp[(size_t)i * 384 + j]       = acc0;
    preVexp[(size_t)i * 384 + 128 + j] = acc1;
    preVexp[(size_t)i * 384 + 256 + j] = acc2;
    if (j == 0) expsum[i] = esum;
}

// ---------------------------------------------------------------------------
// Kernel 6: sequential chain. 1024 threads (16 waves, EXACTLY 4/EU via
// amdgpu_waves_per_eu(4,4) -> VGPR budget 128).
// Every thread owns exactly 64 weights (16 pinned float4):
//   waves 0..11 : W3 rows 0..383, half (w&1)      -> part1
//   waves 12..15: U_h rows 0..127, half ((w-12)&1) -> part3
//
// THIS ROUND: h / htr broadcast moved from global (store + vmcnt(0) drain +
// s_dcache_inv + s_load round trip through L2, ~1300-1500 cyc/step) to LDS
// (ds_write + BARL + uniform-address ds_read_b128 broadcast, ~150 cyc/step).
// x lives in VGPRs (8 live float4 = 32 VGPR; weights 64 VGPR; fits the 128
// budget). The chain-score 64-lane reduce is moved OFF the critical path:
// P4 writes elementwise products to red[], idle wave 12 reduces them during
// the NEXT step's P1 matvec and publishes sScore before the P1-end barrier.
// No global stores remain in the loop -> no vmcnt drains on the chain.
// ---------------------------------------------------------------------------
__global__ __launch_bounds__(1024)
__attribute__((amdgpu_waves_per_eu(4, 4)))
void k_seq(float* __restrict__ ws, const float* __restrict__ Wout,
           const float* __restrict__ bout, const float* __restrict__ y,
           float* __restrict__ out) {
    const int t  = threadIdx.x;
    const int l  = t & 63;
    const int w  = t >> 6;               // wave 0..15
    const bool isP1 = (w < 12);
    const int q1   = w & 1;              // P1 k-half
    const int row1 = 64 * (w >> 1) + l;  // P1 row 0..383
    const int w12  = w - 12;
    const int q3   = w12 & 1;            // P3 k-half
    const int row3 = 64 * (w12 >> 1) + l; // P3 row 0..127

    __shared__ float part1[768];                          // [q][row]
    __shared__ float part3[256];                          // [q][row]
    __shared__ float red[HD];                             // h*wq products
    __shared__ float sScore;                              // reduced chain score
    __shared__ __attribute__((aligned(16))) float h_lds[HD];
    __shared__ __attribute__((aligned(16))) float htr_lds[HD];
    __shared__ float outv[NCLASS];

    // ---- weights: 16 pinned float4 per thread ----
    const int woff = isP1 ? (row1 * HD + 64 * q1)
                          : ((384 + row3) * HD + 64 * q3);
    const float* wp = ws + OFF_W3 + woff;
    float4 A0 = LD4(wp, 0),  A1 = LD4(wp, 1),  A2 = LD4(wp, 2),  A3 = LD4(wp, 3),
           A4 = LD4(wp, 4),  A5 = LD4(wp, 5),  A6 = LD4(wp, 6),  A7 = LD4(wp, 7),
           A8 = LD4(wp, 8),  A9 = LD4(wp, 9),  A10 = LD4(wp, 10), A11 = LD4(wp, 11),
           A12 = LD4(wp, 12), A13 = LD4(wp, 13), A14 = LD4(wp, 14), A15 = LD4(wp, 15);
    PIN_ALL();

    // wave-uniform LDS x base (broadcast reads; conflict-free)
    const float4* xb1 = (const float4*)(h_lds   + 64 * q1);
    const float4* xb3 = (const float4*)(htr_lds + 64 * q3);

    // ---- prefetch registers (t<128 threads own elementwise lane t) ----
    float pv0 = 0.f, pv1 = 0.f, pv2 = 0.f, paz = 0.f, par = 0.f, pah = 0.f,
          pwq = 0.f, pes = 0.f;
    if (t < HD) {
        pv0 = ws[OFF_PREV + t];       pv1 = ws[OFF_PREV + 128 + t];
        pv2 = ws[OFF_PREV + 256 + t];
        paz = ws[OFF_AZ + t];         par = ws[OFF_AR + t];
        pah = ws[OFF_AH + t];
        pwq = ws[OFF_WQ + HD + t];    // wq[1], consumed in P4 of step 0
        pes = ws[OFF_ES];
        h_lds[t] = 0.f;               // h_{-1} = 0
        red[t]   = -1e30f;            // step 0: no chain child -> exp(...) = 0
    }
    __syncthreads();

    float zreg = 0.f, htreg = 0.f, hfin = 0.f, cur_pah = 0.f, cur_pwq = 0.f;

    for (int i = 0; i < NPAR; ++i) {
        const int inext = (i + 1 < NPAR) ? i + 1 : NPAR - 1;
        const int in2   = (i + 2 < NPAR) ? i + 2 : NPAR - 1;

        PIN_ALL();  // in-loop pins: max spill cost for the weight ranges

        // ---- P1: part1[q][row] = W3row . h_half (x via LDS broadcast) ----
        if (isP1) {
            float4 X0 = xb1[0], X1 = xb1[1], X2 = xb1[2], X3 = xb1[3];
            float4 X4 = xb1[4], X5 = xb1[5], X6 = xb1[6], X7 = xb1[7];
            float a0 = 0.f, a1 = 0.f;
            CHV(A0, X0) CHV(A1, X1) CHV(A2, X2) CHV(A3, X3)
            X0 = xb1[8]; X1 = xb1[9]; X2 = xb1[10]; X3 = xb1[11];
            CHV(A4, X4) CHV(A5, X5) CHV(A6, X6) CHV(A7, X7)
            X4 = xb1[12]; X5 = xb1[13]; X6 = xb1[14]; X7 = xb1[15];
            CHV(A8, X0) CHV(A9, X1) CHV(A10, X2) CHV(A11, X3)
            CHV(A12, X4) CHV(A13, X5) CHV(A14, X6) CHV(A15, X7)
            part1[q1 * 384 + row1] = a0 + a1;
        } else if (w == 12) {
            // chain score reduce, overlapped with P1's matvec (wave idle here)
            float s = red[l] + red[l + 64];
#pragma unroll
            for (int o = 32; o > 0; o >>= 1) s += __shfl_down(s, o, 64);
            if (l == 0) sScore = s * SCALE;
        }
        BARL();

        // ---- P2: blend + gates (t<128); htr -> LDS; issue prefetch i+1 ----
        if (t < HD) {
            float vdot = part1[t]       + part1[384 + t];
            float zdot = part1[128 + t] + part1[512 + t];
            float rdot = part1[256 + t] + part1[640 + t];
            float e    = expf(sScore);
            float inv  = 1.f / (pes + e);
            float htv  = (pv0 + e * vdot) * inv;
            float z    = 1.f / (1.f + expf(-(paz + (pv1 + e * zdot) * inv)));
            float rr   = 1.f / (1.f + expf(-(par + (pv2 + e * rdot) * inv)));
            htr_lds[t] = htv * rr;
            zreg = z; htreg = htv;
            // values still needed this step -> temps; then refill prefetches
            // (fire-and-forget global loads; compiler waits before next use)
            cur_pah = pah; cur_pwq = pwq;
            pv0 = ws[OFF_PREV + inext * 384 + t];
            pv1 = ws[OFF_PREV + inext * 384 + 128 + t];
            pv2 = ws[OFF_PREV + inext * 384 + 256 + t];
            paz = ws[OFF_AZ + inext * HD + t];
            par = ws[OFF_AR + inext * HD + t];
            pah = ws[OFF_AH + inext * HD + t];
            pes = ws[OFF_ES + inext];
            pwq = ws[OFF_WQ + in2 * HD + t];
        }
        BARL();

        // ---- P3: part3[q][row] = U_h row . htr_half (LDS broadcast) ----
        if (!isP1) {
            float4 X0 = xb3[0], X1 = xb3[1], X2 = xb3[2], X3 = xb3[3];
            float4 X4 = xb3[4], X5 = xb3[5], X6 = xb3[6], X7 = xb3[7];
            float a0 = 0.f, a1 = 0.f;
            CHV(A0, X0) CHV(A1, X1) CHV(A2, X2) CHV(A3, X3)
            X0 = xb3[8]; X1 = xb3[9]; X2 = xb3[10]; X3 = xb3[11];
            CHV(A4, X4) CHV(A5, X5) CHV(A6, X6) CHV(A7, X7)
            X4 = xb3[12]; X5 = xb3[13]; X6 = xb3[14]; X7 = xb3[15];
            CHV(A8, X0) CHV(A9, X1) CHV(A10, X2) CHV(A11, X3)
            CHV(A12, X4) CHV(A13, X5) CHV(A14, X6) CHV(A15, X7)
            part3[q3 * 128 + row3] = a0 + a1;
        }
        BARL();

        // ---- P4: finalize h (t<128); h -> LDS; score products -> red[] ----
        if (t < HD) {
            float u  = part3[t] + part3[128 + t];
            float c  = tanhf(cur_pah + u);
            float hv = zreg * htreg + (1.f - zreg) * c;
            hfin = hv;
            h_lds[t] = hv;
            red[t]   = hv * cur_pwq;   // <h_i, wq_{i+1}> products; reduced
                                       // by wave 12 during next P1
        }
        BARL();
    }

    // ---- output head ----
    if (t < NCLASS) {
        float acc = bout[t];
#pragma unroll 4
        for (int k = 0; k < HD; ++k) acc += Wout[(size_t)t * HD + k] * h_lds[k];
        outv[t] = acc;
    }
    __syncthreads();
    if (t == 0) {
        float m  = fmaxf(fmaxf(outv[0], outv[1]), fmaxf(outv[2], outv[3]));
        float e0 = expf(outv[0] - m), e1 = expf(outv[1] - m);
        float e2 = expf(outv[2] - m), e3 = expf(outv[3] - m);
        float inv = 1.f / (e0 + e1 + e2 + e3);
        float p0 = e0 * inv, p1 = e1 * inv, p2 = e2 * inv, p3 = e3 * inv;
        out[0] = p0; out[1] = p1; out[2] = p2; out[3] = p3;
        float d0 = y[0] - p0, d1 = y[1] - p1, d2 = y[2] - p2, d3 = y[3] - p3;
        out[4] = d0 * d0 + d1 * d1 + d2 * d2 + d3 * d3;
    }
}

// ---------------------------------------------------------------------------
extern "C" void kernel_launch(void* const* d_in, const int* in_sizes, int n_in,
                              void* d_out, int out_size, void* d_ws, size_t ws_size,
                              hipStream_t stream) {
    const float* x_word  = (const float*)d_in[0];
    const int*   x_index = (const int*)d_in[1];
    const int*   tree    = (const int*)d_in[2];
    const float* y       = (const float*)d_in[3];
    const float* E_bu    = (const float*)d_in[4];
    const float* WQ      = (const float*)d_in[5];
    const float* WK      = (const float*)d_in[6];
    const float* WV      = (const float*)d_in[7];
    const float* W_z     = (const float*)d_in[8];
    const float* U_z     = (const float*)d_in[9];
    const float* b_z     = (const float*)d_in[10];
    const float* W_r     = (const float*)d_in[11];
    const float* U_r     = (const float*)d_in[12];
    const float* b_r     = (const float*)d_in[13];
    const float* W_h     = (const float*)d_in[14];
    const float* U_h     = (const float*)d_in[15];
    const float* b_h     = (const float*)d_in[16];
    const float* W_out   = (const float*)d_in[17];
    const float* b_out   = (const float*)d_in[18];

    float* ws      = (float*)d_ws;
    float* xe      = ws + OFF_XE;
    float* node_h  = ws + OFF_NODE;
    float* w3      = ws + OFF_W3;
    float* wq      = ws + OFF_WQ;
    float* az      = ws + OFF_AZ;
    float* ar      = ws + OFF_AR;
    float* ah      = ws + OFF_AH;
    float* preVexp = ws + OFF_PREV;
    float* expsum  = ws + OFF_ES;
    float* ET      = ws + OFF_ET;

    bool use_transpose = ws_size >= WS_END * sizeof(float);

    if (use_transpose) {
        dim3 tg(VOCABN / 32, HD / 32), tb(32, 8);
        k_transpose<<<tg, tb, 0, stream>>>(E_bu, ET);
        k_xe_t<<<NNODE, HD, 0, stream>>>(x_word, x_index, ET, xe);
    } else {
        k_xe<<<NNODE, HD, 0, stream>>>(x_word, x_index, E_bu, xe);
    }
    k_leaf<<<NLEAF, HD, 0, stream>>>(xe, W_z, b_z, W_h, b_h, node_h);
    k_fuse<<<512, HD, 0, stream>>>(WV, U_z, U_r, U_h, w3);
    k_ppre<<<NPAR, HD, 0, stream>>>(xe, WQ, WK, W_z, b_z, W_r, b_r, W_h, b_h,
                                    wq, az, ar, ah);
    k_chpre<<<NPAR, HD, 0, stream>>>(tree, node_h, w3, wq, preVexp, expsum);
    k_seq<<<1, 1024, 0, stream>>>(ws, W_out, b_out, y, (float*)d_out);
}

// Round 2
// 4412.277 us; speedup vs baseline: 1.1001x; 1.1001x over previous
//
#include <hip/hip_runtime.h>
#include <math.h>

#define HD 128
#define LW 32
#define VOCABN 200000
#define NLEAF 2048
#define NPAR 2047
#define NNODE 4095
#define MAXC 4
#define NCLASS 4
#define SCALE 0.08838834764831845f  // 1/sqrt(128)

// Workspace layout (floats), compile-time offsets => k_seq needs ONE base ptr
#define OFF_XE   0
#define OFF_NODE 524160    // + NNODE*HD
#define OFF_W3   786304    // + NLEAF*HD
#define OFF_WQ   851840    // + 512*HD
#define OFF_AZ   1113856   // + NPAR*HD
#define OFF_AR   1375872
#define OFF_AH   1637888
#define OFF_PREV 1899904
#define OFF_ES   2685952   // + NPAR*384
#define OFF_HG   2688000   // unused by k_seq now; layout kept stable
#define OFF_HTR  2688128
#define OFF_ET   2688256
#define WS_END   (OFF_ET + (size_t)VOCABN * HD)

// LDS-only barrier: lgkmcnt(0) makes ds_writes visible, does NOT drain vmcnt
// (prefetch global loads stay in flight across it).
#define BARL() asm volatile("s_waitcnt lgkmcnt(0)\n\ts_barrier" ::: "memory")
// Pin float4 into VGPRs component-wise.
#define PIN4(v) asm volatile("" : "+v"((v).x), "+v"((v).y), "+v"((v).z), "+v"((v).w))
#define LD4(p, k) (*(const float4*)((p) + 4 * (k)))

#define PIN_ALL() do { PIN4(A0); PIN4(A1); PIN4(A2); PIN4(A3); \
    PIN4(A4); PIN4(A5); PIN4(A6); PIN4(A7); PIN4(A8); PIN4(A9); \
    PIN4(A10); PIN4(A11); PIN4(A12); PIN4(A13); PIN4(A14); PIN4(A15); } while (0)

// Broadcast x[B..B+3] from per-lane register (lane j holds x[j]) into SGPR
// uniforms via v_readlane, then 4 MACs. One SGPR operand per v_fma -> legal.
#define CHRL(W, B) { \
    float s0_ = __int_as_float(__builtin_amdgcn_readlane(xi_, (B) + 0)); \
    float s1_ = __int_as_float(__builtin_amdgcn_readlane(xi_, (B) + 1)); \
    float s2_ = __int_as_float(__builtin_amdgcn_readlane(xi_, (B) + 2)); \
    float s3_ = __int_as_float(__builtin_amdgcn_readlane(xi_, (B) + 3)); \
    a0 += (W).x * s0_ + (W).y * s1_; a1 += (W).z * s2_ + (W).w * s3_; }

#define MATVEC_RL() do { \
    CHRL(A0, 0)   CHRL(A1, 4)   CHRL(A2, 8)   CHRL(A3, 12) \
    CHRL(A4, 16)  CHRL(A5, 20)  CHRL(A6, 24)  CHRL(A7, 28) \
    CHRL(A8, 32)  CHRL(A9, 36)  CHRL(A10, 40) CHRL(A11, 44) \
    CHRL(A12, 48) CHRL(A13, 52) CHRL(A14, 56) CHRL(A15, 60) } while (0)

// ---------------------------------------------------------------------------
// Kernel 1a (fallback): xe via uncoalesced gather
// ---------------------------------------------------------------------------
__global__ void k_xe(const float* __restrict__ xw, const int* __restrict__ xi,
                     const float* __restrict__ E, float* __restrict__ xe) {
    int n = blockIdx.x;
    int h = threadIdx.x;
    __shared__ int   sidx[LW];
    __shared__ float sw[LW];
    if (h < LW) { sidx[h] = xi[n * LW + h]; sw[h] = xw[n * LW + h]; }
    __syncthreads();
    float acc = 0.f;
#pragma unroll
    for (int l = 0; l < LW; ++l)
        acc += E[(size_t)h * VOCABN + sidx[l]] * sw[l];
    xe[(size_t)n * HD + h] = acc;
}

// ---------------------------------------------------------------------------
// Kernel 1b: transpose E (H x VOCAB) -> ET (VOCAB x H)
// ---------------------------------------------------------------------------
__global__ void k_transpose(const float* __restrict__ E, float* __restrict__ ET) {
    __shared__ float tile[32][33];
    int vb = blockIdx.x * 32, hb = blockIdx.y * 32;
    int tx = threadIdx.x, ty = threadIdx.y;  // 32 x 8
#pragma unroll
    for (int r = 0; r < 32; r += 8)
        tile[ty + r][tx] = E[(size_t)(hb + ty + r) * VOCABN + vb + tx];
    __syncthreads();
#pragma unroll
    for (int r = 0; r < 32; r += 8)
        ET[(size_t)(vb + ty + r) * HD + hb + tx] = tile[tx][ty + r];
}

// Kernel 1c: coalesced gather+reduce from ET.
__global__ void k_xe_t(const float* __restrict__ xw, const int* __restrict__ xi,
                       const float* __restrict__ ET, float* __restrict__ xe) {
    int n = blockIdx.x;
    int h = threadIdx.x;
    __shared__ int   sidx[LW];
    __shared__ float sw[LW];
    if (h < LW) { sidx[h] = xi[n * LW + h]; sw[h] = xw[n * LW + h]; }
    __syncthreads();
    float acc = 0.f;
#pragma unroll
    for (int l = 0; l < LW; ++l)
        acc += ET[(size_t)sidx[l] * HD + h] * sw[l];
    xe[(size_t)n * HD + h] = acc;
}

// ---------------------------------------------------------------------------
// Kernel 2: leaf cells -> node_h[0:NLEAF]
// ---------------------------------------------------------------------------
__global__ void k_leaf(const float* __restrict__ xe, const float* __restrict__ Wz,
                       const float* __restrict__ bz, const float* __restrict__ Wh,
                       const float* __restrict__ bh, float* __restrict__ node_h) {
    int n = blockIdx.x;
    int j = threadIdx.x;
    __shared__ float xl[HD];
    xl[j] = xe[(size_t)n * HD + j];
    __syncthreads();
    float az = bz[j], ah = bh[j];
    const float* wzr = Wz + (size_t)j * HD;
    const float* whr = Wh + (size_t)j * HD;
#pragma unroll 4
    for (int k = 0; k < HD; ++k) { az += wzr[k] * xl[k]; ah += whr[k] * xl[k]; }
    float z = 1.f / (1.f + expf(-az));
    float c = tanhf(ah);
    node_h[(size_t)n * HD + j] = (1.f - z) * c;
}

// ---------------------------------------------------------------------------
// Kernel 3: fused weight stack W3 (512 x 128):
//   rows 0..127: WV^T / 128..255: U_z WV^T / 256..383: U_r WV^T / 384..511: U_h
// ---------------------------------------------------------------------------
__global__ void k_fuse(const float* __restrict__ WV, const float* __restrict__ Uz,
                       const float* __restrict__ Ur, const float* __restrict__ Uh,
                       float* __restrict__ w3) {
    int r = blockIdx.x;
    int b = threadIdx.x;
    float v;
    if (r < 128) {
        v = WV[(size_t)b * HD + r];
    } else if (r < 384) {
        const float* u  = (r < 256 ? Uz + (size_t)(r - 128) * HD : Ur + (size_t)(r - 256) * HD);
        const float* wv = WV + (size_t)b * HD;
        float a = 0.f;
#pragma unroll 4
        for (int j = 0; j < HD; ++j) a += u[j] * wv[j];
        v = a;
    } else {
        v = Uh[(size_t)(r - 384) * HD + b];
    }
    w3[(size_t)r * HD + b] = v;
}

// ---------------------------------------------------------------------------
// Kernel 4: per-parent precompute
// ---------------------------------------------------------------------------
__global__ void k_ppre(const float* __restrict__ xe, const float* __restrict__ WQ,
                       const float* __restrict__ WK, const float* __restrict__ Wz,
                       const float* __restrict__ bz, const float* __restrict__ Wr,
                       const float* __restrict__ br, const float* __restrict__ Wh,
                       const float* __restrict__ bh, float* __restrict__ wq,
                       float* __restrict__ az, float* __restrict__ ar,
                       float* __restrict__ ah) {
    int i = blockIdx.x;
    int j = threadIdx.x;
    __shared__ float xl[HD], ql[HD];
    xl[j] = xe[(size_t)(NLEAF + i) * HD + j];
    __syncthreads();
    float q = 0.f;
#pragma unroll 4
    for (int h = 0; h < HD; ++h) q += xl[h] * WQ[(size_t)h * HD + j];
    ql[j] = 1.f / (1.f + expf(-q));
    __syncthreads();
    float w = 0.f;
#pragma unroll 4
    for (int k = 0; k < HD; ++k) w += WK[(size_t)j * HD + k] * ql[k];
    wq[(size_t)i * HD + j] = w;
    float vz = bz[j], vr = br[j], vh = bh[j];
#pragma unroll 4
    for (int k = 0; k < HD; ++k) {
        float xv = xl[k];
        vz += Wz[(size_t)j * HD + k] * xv;
        vr += Wr[(size_t)j * HD + k] * xv;
        vh += Wh[(size_t)j * HD + k] * xv;
    }
    az[(size_t)i * HD + j] = vz;
    ar[(size_t)i * HD + j] = vr;
    ah[(size_t)i * HD + j] = vh;
}

// ---------------------------------------------------------------------------
// Kernel 5: aggregated leaf-child precompute per parent
// ---------------------------------------------------------------------------
__global__ void k_chpre(const int* __restrict__ tree, const float* __restrict__ node_h,
                        const float* __restrict__ w3, const float* __restrict__ wq_all,
                        float* __restrict__ preVexp, float* __restrict__ expsum) {
    int i = blockIdx.x;
    int j = threadIdx.x;
    __shared__ float hl[HD];
    __shared__ float red[HD];
    float wqj = wq_all[(size_t)i * HD + j];
    float acc0 = 0.f, acc1 = 0.f, acc2 = 0.f, esum = 0.f;
    for (int c = 0; c < MAXC; ++c) {
        int child = tree[i * MAXC + c];
        if (child < 0 || child >= NLEAF) continue;  // uniform per block
        __syncthreads();
        hl[j] = node_h[(size_t)child * HD + j];
        __syncthreads();
        red[j] = hl[j] * wqj;
        __syncthreads();
        for (int s = 64; s > 0; s >>= 1) {
            if (j < s) red[j] += red[j + s];
            __syncthreads();
        }
        float e = expf(red[0] * SCALE);
        float d0 = 0.f, d1 = 0.f, d2 = 0.f;
#pragma unroll 4
        for (int k = 0; k < HD; ++k) {
            float x = hl[k];
            d0 += w3[(size_t)j * HD + k] * x;
            d1 += w3[(size_t)(128 + j) * HD + k] * x;
            d2 += w3[(size_t)(256 + j) * HD + k] * x;
        }
        acc0 += e * d0; acc1 += e * d1; acc2 += e * d2; esum += e;
    }
    preVexp[(size_t)i * 384 + j]       = acc0;
    preVexp[(size_t)i * 384 + 128 + j] = acc1;
    preVexp[(size_t)i * 384 + 256 + j] = acc2;
    if (j == 0) expsum[i] = esum;
}

// ---------------------------------------------------------------------------
// Kernel 6: sequential chain. 1024 threads (16 waves, 4/EU via
// amdgpu_waves_per_eu(4,4) -> VGPR budget 128). Each thread owns 64 weights
// (16 pinned float4):
//   waves 0..11 : W3 rows 0..383, half (w&1)       -> part1
//   waves 12..15: U_h rows 0..127, half ((w-12)&1) -> part3
//
// THIS ROUND: no global stores / s_dcache_inv / vmcnt drains in the loop.
// EVERY wave computes the elementwise phases redundantly for its own
// 64-element half (m = 64*q + lane), so h[m] / htr[m] end up in the wave's
// own lanes; v_readlane then moves them into SGPRs for the matvec (free
// broadcast as FMA scalar operand). This replaces the two ~1000-cycle L2
// round trips of the store+s_load scheme with pure in-register movement.
// Round-1 lesson: uniform ds_read_b128 broadcast is NOT cheap (1KB RF
// delivery per instr through the shared LDS pipe) -- avoided here.
// 3 phases / 3 LDS-only barriers per step.
// ---------------------------------------------------------------------------
__global__ __launch_bounds__(1024)
__attribute__((amdgpu_waves_per_eu(4, 4)))
void k_seq(float* __restrict__ ws, const float* __restrict__ Wout,
           const float* __restrict__ bout, const float* __restrict__ y,
           float* __restrict__ out) {
    const int t  = threadIdx.x;
    const int l  = t & 63;
    const int w  = t >> 6;               // wave 0..15
    const bool isP1 = (w < 12);
    const int q1   = w & 1;              // P1 k-half
    const int row1 = 64 * (w >> 1) + l;  // P1 row 0..383
    const int w12  = w - 12;
    const int q3   = w12 & 1;            // P3 k-half
    const int row3 = 64 * (w12 >> 1) + l; // P3 row 0..127
    const int q    = isP1 ? q1 : q3;
    const int m    = 64 * q + l;         // this wave's elementwise lane

    __shared__ float part1[768];         // [q][row]
    __shared__ float part3[256];         // [q][row]
    __shared__ float red[HD];            // h*wq products (for next score)
    __shared__ float sScore;             // reduced chain score * SCALE
    __shared__ float hfin[HD];
    __shared__ float outv[NCLASS];

    // ---- weights: 16 pinned float4 per thread ----
    const int woff = isP1 ? (row1 * HD + 64 * q1)
                          : ((384 + row3) * HD + 64 * q3);
    const float* wp = ws + OFF_W3 + woff;
    float4 A0 = LD4(wp, 0),  A1 = LD4(wp, 1),  A2 = LD4(wp, 2),  A3 = LD4(wp, 3),
           A4 = LD4(wp, 4),  A5 = LD4(wp, 5),  A6 = LD4(wp, 6),  A7 = LD4(wp, 7),
           A8 = LD4(wp, 8),  A9 = LD4(wp, 9),  A10 = LD4(wp, 10), A11 = LD4(wp, 11),
           A12 = LD4(wp, 12), A13 = LD4(wp, 13), A14 = LD4(wp, 14), A15 = LD4(wp, 15);
    PIN_ALL();

    // ---- per-wave prefetch registers for element m ----
    float pv0 = ws[OFF_PREV + m];
    float pv1 = ws[OFF_PREV + 128 + m];
    float pv2 = ws[OFF_PREV + 256 + m];
    float paz = ws[OFF_AZ + m];
    float par = ws[OFF_AR + m];
    float pah = ws[OFF_AH + m];
    float pes = ws[OFF_ES];
    float pwq = ws[OFF_WQ + HD + m];     // wq[1], consumed in phase C of step 0

    float h_lane = 0.f;                  // h_{-1}[m] = 0
    if (t < HD) red[t] = (t < 64) ? -1e30f : 0.f;  // step 0: no chain child
    __syncthreads();

    float zreg = 0.f, htvreg = 0.f;

    for (int i = 0; i < NPAR; ++i) {
        const int inext = (i + 1 < NPAR) ? i + 1 : NPAR - 1;
        const int in2   = (i + 2 < NPAR) ? i + 2 : NPAR - 1;

        PIN_ALL();

        // ---- Phase A: P1 matvec (readlane h from own lanes); wave 12
        //      reduces chain score concurrently ----
        if (isP1) {
            const int xi_ = __float_as_int(h_lane);
            float a0 = 0.f, a1 = 0.f;
            MATVEC_RL();
            part1[q1 * 384 + row1] = a0 + a1;
        } else if (w == 12) {
            float s = red[l] + red[l + 64];
#pragma unroll
            for (int o = 32; o > 0; o >>= 1) s += __shfl_down(s, o, 64);
            if (l == 0) sScore = s * SCALE;
        }
        BARL();

        // ---- Phase B: ALL waves: redundant gates for element m;
        //      P3 waves then matvec U_h . htr via readlane ----
        {
            float sc  = sScore;
            float e   = expf(sc);
            float vd  = part1[m]       + part1[384 + m];
            float zd  = part1[128 + m] + part1[512 + m];
            float rd  = part1[256 + m] + part1[640 + m];
            float inv = 1.f / (pes + e);
            float htv = (pv0 + e * vd) * inv;
            float z   = 1.f / (1.f + expf(-(paz + (pv1 + e * zd) * inv)));
            float rr  = 1.f / (1.f + expf(-(par + (pv2 + e * rd) * inv)));
            float htr = htv * rr;
            zreg = z; htvreg = htv;
            if (!isP1) {
                const int xi_ = __float_as_int(htr);
                float a0 = 0.f, a1 = 0.f;
                MATVEC_RL();
                part3[q3 * 128 + row3] = a0 + a1;
            }
        }
        BARL();

        // ---- Phase C: ALL waves: finalize h[m]; waves 0,1 publish score
        //      products; refill prefetches (fire-and-forget) ----
        {
            float u  = part3[m] + part3[128 + m];
            float c  = tanhf(pah + u);
            float hv = zreg * htvreg + (1.f - zreg) * c;
            h_lane = hv;
            if (w < 2) red[m] = hv * pwq;   // <h_i, wq_{i+1}> products
        }
        pv0 = ws[OFF_PREV + inext * 384 + m];
        pv1 = ws[OFF_PREV + inext * 384 + 128 + m];
        pv2 = ws[OFF_PREV + inext * 384 + 256 + m];
        paz = ws[OFF_AZ + inext * HD + m];
        par = ws[OFF_AR + inext * HD + m];
        pah = ws[OFF_AH + inext * HD + m];
        pes = ws[OFF_ES + inext];
        pwq = ws[OFF_WQ + in2 * HD + m];
        BARL();
    }

    // ---- output head ----
    if (w < 2) hfin[m] = h_lane;
    __syncthreads();
    if (t < NCLASS) {
        float acc = bout[t];
#pragma unroll 4
        for (int k = 0; k < HD; ++k) acc += Wout[(size_t)t * HD + k] * hfin[k];
        outv[t] = acc;
    }
    __syncthreads();
    if (t == 0) {
        float mx = fmaxf(fmaxf(outv[0], outv[1]), fmaxf(outv[2], outv[3]));
        float e0 = expf(outv[0] - mx), e1 = expf(outv[1] - mx);
        float e2 = expf(outv[2] - mx), e3 = expf(outv[3] - mx);
        float inv = 1.f / (e0 + e1 + e2 + e3);
        float p0 = e0 * inv, p1 = e1 * inv, p2 = e2 * inv, p3 = e3 * inv;
        out[0] = p0; out[1] = p1; out[2] = p2; out[3] = p3;
        float d0 = y[0] - p0, d1 = y[1] - p1, d2 = y[2] - p2, d3 = y[3] - p3;
        out[4] = d0 * d0 + d1 * d1 + d2 * d2 + d3 * d3;
    }
}

// ---------------------------------------------------------------------------
extern "C" void kernel_launch(void* const* d_in, const int* in_sizes, int n_in,
                              void* d_out, int out_size, void* d_ws, size_t ws_size,
                              hipStream_t stream) {
    const float* x_word  = (const float*)d_in[0];
    const int*   x_index = (const int*)d_in[1];
    const int*   tree    = (const int*)d_in[2];
    const float* y       = (const float*)d_in[3];
    const float* E_bu    = (const float*)d_in[4];
    const float* WQ      = (const float*)d_in[5];
    const float* WK      = (const float*)d_in[6];
    const float* WV      = (const float*)d_in[7];
    const float* W_z     = (const float*)d_in[8];
    const float* U_z     = (const float*)d_in[9];
    const float* b_z     = (const float*)d_in[10];
    const float* W_r     = (const float*)d_in[11];
    const float* U_r     = (const float*)d_in[12];
    const float* b_r     = (const float*)d_in[13];
    const float* W_h     = (const float*)d_in[14];
    const float* U_h     = (const float*)d_in[15];
    const float* b_h     = (const float*)d_in[16];
    const float* W_out   = (const float*)d_in[17];
    const float* b_out   = (const float*)d_in[18];

    float* ws      = (float*)d_ws;
    float* xe      = ws + OFF_XE;
    float* node_h  = ws + OFF_NODE;
    float* w3      = ws + OFF_W3;
    float* wq      = ws + OFF_WQ;
    float* az      = ws + OFF_AZ;
    float* ar      = ws + OFF_AR;
    float* ah      = ws + OFF_AH;
    float* preVexp = ws + OFF_PREV;
    float* expsum  = ws + OFF_ES;
    float* ET      = ws + OFF_ET;

    bool use_transpose = ws_size >= WS_END * sizeof(float);

    if (use_transpose) {
        dim3 tg(VOCABN / 32, HD / 32), tb(32, 8);
        k_transpose<<<tg, tb, 0, stream>>>(E_bu, ET);
        k_xe_t<<<NNODE, HD, 0, stream>>>(x_word, x_index, ET, xe);
    } else {
        k_xe<<<NNODE, HD, 0, stream>>>(x_word, x_index, E_bu, xe);
    }
    k_leaf<<<NLEAF, HD, 0, stream>>>(xe, W_z, b_z, W_h, b_h, node_h);
    k_fuse<<<512, HD, 0, stream>>>(WV, U_z, U_r, U_h, w3);
    k_ppre<<<NPAR, HD, 0, stream>>>(xe, WQ, WK, W_z, b_z, W_r, b_r, W_h, b_h,
                                    wq, az, ar, ah);
    k_chpre<<<NPAR, HD, 0, stream>>>(tree, node_h, w3, wq, preVexp, expsum);
    k_seq<<<1, 1024, 0, stream>>>(ws, W_out, b_out, y, (float*)d_out);
}

// Round 3
// 3660.952 us; speedup vs baseline: 1.3259x; 1.2052x over previous
//
#include <hip/hip_runtime.h>
#include <math.h>

#define HD 128
#define LW 32
#define VOCABN 200000
#define NLEAF 2048
#define NPAR 2047
#define NNODE 4095
#define MAXC 4
#define NCLASS 4
#define SCALE 0.08838834764831845f  // 1/sqrt(128)

// Workspace layout (floats), compile-time offsets => k_seq needs ONE base ptr
#define OFF_XE   0
#define OFF_NODE 524160    // + NNODE*HD
#define OFF_W3   786304    // + NLEAF*HD
#define OFF_WQ   851840    // + 512*HD
#define OFF_AZ   1113856   // + NPAR*HD
#define OFF_AR   1375872
#define OFF_AH   1637888
#define OFF_PREV 1899904
#define OFF_ES   2685952   // + NPAR*384
#define OFF_HG   2688000   // unused by k_seq now; layout kept stable
#define OFF_HTR  2688128
#define OFF_ET   2688256
#define WS_END   (OFF_ET + (size_t)VOCABN * HD)

// LDS-only barrier: lgkmcnt(0) makes ds_writes visible, does NOT drain vmcnt
// (prefetch global loads stay in flight across it).
#define BARL() asm volatile("s_waitcnt lgkmcnt(0)\n\ts_barrier" ::: "memory")
// Pin float4 into VGPRs component-wise.
#define PIN4(v) asm volatile("" : "+v"((v).x), "+v"((v).y), "+v"((v).z), "+v"((v).w))
#define LD4(p, k) (*(const float4*)((p) + 4 * (k)))

#define PIN_ALL() do { PIN4(A0); PIN4(A1); PIN4(A2); PIN4(A3); \
    PIN4(A4); PIN4(A5); PIN4(A6); PIN4(A7); PIN4(A8); PIN4(A9); \
    PIN4(A10); PIN4(A11); PIN4(A12); PIN4(A13); PIN4(A14); PIN4(A15); } while (0)

#define RL(x, j) __int_as_float(__builtin_amdgcn_readlane((x), (j)))

// 4 shared scalars feed TWO rows (A-row via WA regs, B-row via WB regs).
#define CH2(WA, WB, XS, J) { \
    float s0_ = RL(XS, (J) + 0), s1_ = RL(XS, (J) + 1); \
    float s2_ = RL(XS, (J) + 2), s3_ = RL(XS, (J) + 3); \
    a0 += (WA).x * s0_ + (WA).y * s1_; a1 += (WA).z * s2_ + (WA).w * s3_; \
    b0 += (WB).x * s0_ + (WB).y * s1_; b1 += (WB).z * s2_ + (WB).w * s3_; }

// 2-row x 32-K matvec: 32 readlanes (compile-time lanes BASE..BASE+31), 64 FMA
#define MATVEC2(XS, BASE) do { \
    CH2(A0, A8,  XS, (BASE) + 0)  CH2(A1, A9,  XS, (BASE) + 4)  \
    CH2(A2, A10, XS, (BASE) + 8)  CH2(A3, A11, XS, (BASE) + 12) \
    CH2(A4, A12, XS, (BASE) + 16) CH2(A5, A13, XS, (BASE) + 20) \
    CH2(A6, A14, XS, (BASE) + 24) CH2(A7, A15, XS, (BASE) + 28) } while (0)

// ---------------------------------------------------------------------------
// Kernel 1a (fallback): xe via uncoalesced gather
// ---------------------------------------------------------------------------
__global__ void k_xe(const float* __restrict__ xw, const int* __restrict__ xi,
                     const float* __restrict__ E, float* __restrict__ xe) {
    int n = blockIdx.x;
    int h = threadIdx.x;
    __shared__ int   sidx[LW];
    __shared__ float sw[LW];
    if (h < LW) { sidx[h] = xi[n * LW + h]; sw[h] = xw[n * LW + h]; }
    __syncthreads();
    float acc = 0.f;
#pragma unroll
    for (int l = 0; l < LW; ++l)
        acc += E[(size_t)h * VOCABN + sidx[l]] * sw[l];
    xe[(size_t)n * HD + h] = acc;
}

// ---------------------------------------------------------------------------
// Kernel 1b: transpose E (H x VOCAB) -> ET (VOCAB x H)
// ---------------------------------------------------------------------------
__global__ void k_transpose(const float* __restrict__ E, float* __restrict__ ET) {
    __shared__ float tile[32][33];
    int vb = blockIdx.x * 32, hb = blockIdx.y * 32;
    int tx = threadIdx.x, ty = threadIdx.y;  // 32 x 8
#pragma unroll
    for (int r = 0; r < 32; r += 8)
        tile[ty + r][tx] = E[(size_t)(hb + ty + r) * VOCABN + vb + tx];
    __syncthreads();
#pragma unroll
    for (int r = 0; r < 32; r += 8)
        ET[(size_t)(vb + ty + r) * HD + hb + tx] = tile[tx][ty + r];
}

// Kernel 1c: coalesced gather+reduce from ET.
__global__ void k_xe_t(const float* __restrict__ xw, const int* __restrict__ xi,
                       const float* __restrict__ ET, float* __restrict__ xe) {
    int n = blockIdx.x;
    int h = threadIdx.x;
    __shared__ int   sidx[LW];
    __shared__ float sw[LW];
    if (h < LW) { sidx[h] = xi[n * LW + h]; sw[h] = xw[n * LW + h]; }
    __syncthreads();
    float acc = 0.f;
#pragma unroll
    for (int l = 0; l < LW; ++l)
        acc += ET[(size_t)sidx[l] * HD + h] * sw[l];
    xe[(size_t)n * HD + h] = acc;
}

// ---------------------------------------------------------------------------
// Kernel 2: leaf cells -> node_h[0:NLEAF]
// ---------------------------------------------------------------------------
__global__ void k_leaf(const float* __restrict__ xe, const float* __restrict__ Wz,
                       const float* __restrict__ bz, const float* __restrict__ Wh,
                       const float* __restrict__ bh, float* __restrict__ node_h) {
    int n = blockIdx.x;
    int j = threadIdx.x;
    __shared__ float xl[HD];
    xl[j] = xe[(size_t)n * HD + j];
    __syncthreads();
    float az = bz[j], ah = bh[j];
    const float* wzr = Wz + (size_t)j * HD;
    const float* whr = Wh + (size_t)j * HD;
#pragma unroll 4
    for (int k = 0; k < HD; ++k) { az += wzr[k] * xl[k]; ah += whr[k] * xl[k]; }
    float z = 1.f / (1.f + expf(-az));
    float c = tanhf(ah);
    node_h[(size_t)n * HD + j] = (1.f - z) * c;
}

// ---------------------------------------------------------------------------
// Kernel 3: fused weight stack W3 (512 x 128):
//   rows 0..127: WV^T / 128..255: U_z WV^T / 256..383: U_r WV^T / 384..511: U_h
// ---------------------------------------------------------------------------
__global__ void k_fuse(const float* __restrict__ WV, const float* __restrict__ Uz,
                       const float* __restrict__ Ur, const float* __restrict__ Uh,
                       float* __restrict__ w3) {
    int r = blockIdx.x;
    int b = threadIdx.x;
    float v;
    if (r < 128) {
        v = WV[(size_t)b * HD + r];
    } else if (r < 384) {
        const float* u  = (r < 256 ? Uz + (size_t)(r - 128) * HD : Ur + (size_t)(r - 256) * HD);
        const float* wv = WV + (size_t)b * HD;
        float a = 0.f;
#pragma unroll 4
        for (int j = 0; j < HD; ++j) a += u[j] * wv[j];
        v = a;
    } else {
        v = Uh[(size_t)(r - 384) * HD + b];
    }
    w3[(size_t)r * HD + b] = v;
}

// ---------------------------------------------------------------------------
// Kernel 4: per-parent precompute
// ---------------------------------------------------------------------------
__global__ void k_ppre(const float* __restrict__ xe, const float* __restrict__ WQ,
                       const float* __restrict__ WK, const float* __restrict__ Wz,
                       const float* __restrict__ bz, const float* __restrict__ Wr,
                       const float* __restrict__ br, const float* __restrict__ Wh,
                       const float* __restrict__ bh, float* __restrict__ wq,
                       float* __restrict__ az, float* __restrict__ ar,
                       float* __restrict__ ah) {
    int i = blockIdx.x;
    int j = threadIdx.x;
    __shared__ float xl[HD], ql[HD];
    xl[j] = xe[(size_t)(NLEAF + i) * HD + j];
    __syncthreads();
    float q = 0.f;
#pragma unroll 4
    for (int h = 0; h < HD; ++h) q += xl[h] * WQ[(size_t)h * HD + j];
    ql[j] = 1.f / (1.f + expf(-q));
    __syncthreads();
    float w = 0.f;
#pragma unroll 4
    for (int k = 0; k < HD; ++k) w += WK[(size_t)j * HD + k] * ql[k];
    wq[(size_t)i * HD + j] = w;
    float vz = bz[j], vr = br[j], vh = bh[j];
#pragma unroll 4
    for (int k = 0; k < HD; ++k) {
        float xv = xl[k];
        vz += Wz[(size_t)j * HD + k] * xv;
        vr += Wr[(size_t)j * HD + k] * xv;
        vh += Wh[(size_t)j * HD + k] * xv;
    }
    az[(size_t)i * HD + j] = vz;
    ar[(size_t)i * HD + j] = vr;
    ah[(size_t)i * HD + j] = vh;
}

// ---------------------------------------------------------------------------
// Kernel 5: aggregated leaf-child precompute per parent
// ---------------------------------------------------------------------------
__global__ void k_chpre(const int* __restrict__ tree, const float* __restrict__ node_h,
                        const float* __restrict__ w3, const float* __restrict__ wq_all,
                        float* __restrict__ preVexp, float* __restrict__ expsum) {
    int i = blockIdx.x;
    int j = threadIdx.x;
    __shared__ float hl[HD];
    __shared__ float red[HD];
    float wqj = wq_all[(size_t)i * HD + j];
    float acc0 = 0.f, acc1 = 0.f, acc2 = 0.f, esum = 0.f;
    for (int c = 0; c < MAXC; ++c) {
        int child = tree[i * MAXC + c];
        if (child < 0 || child >= NLEAF) continue;  // uniform per block
        __syncthreads();
        hl[j] = node_h[(size_t)child * HD + j];
        __syncthreads();
        red[j] = hl[j] * wqj;
        __syncthreads();
        for (int s = 64; s > 0; s >>= 1) {
            if (j < s) red[j] += red[j + s];
            __syncthreads();
        }
        float e = expf(red[0] * SCALE);
        float d0 = 0.f, d1 = 0.f, d2 = 0.f;
#pragma unroll 4
        for (int k = 0; k < HD; ++k) {
            float x = hl[k];
            d0 += w3[(size_t)j * HD + k] * x;
            d1 += w3[(size_t)(128 + j) * HD + k] * x;
            d2 += w3[(size_t)(256 + j) * HD + k] * x;
        }
        acc0 += e * d0; acc1 += e * d1; acc2 += e * d2; esum += e;
    }
    preVexp[(size_t)i * 384 + j]       = acc0;
    preVexp[(size_t)i * 384 + 128 + j] = acc1;
    preVexp[(size_t)i * 384 + 256 + j] = acc2;
    if (j == 0) expsum[i] = esum;
}

// ---------------------------------------------------------------------------
// Kernel 6: sequential chain. 1024 threads (16 waves, 4/EU). Round-2 lesson:
// the lane-local-h structure (no global stores, no dcache_inv, no vmcnt
// drains) is right, but 64 readlanes/matvec + gates on all 16 waves made it
// ISSUE-bound (VALUBusy 0.12->0.32 at equal time). This round cuts issue:
//  - matvec = 2 rows x 32-K per thread: 32 readlanes shared by 2 rows
//    (issue per P1 wave ~100 instr vs 128; same 64 weights/thread).
//  - gates computed ONLY by the 4 P3 waves; P1 waves get h via one per-lane
//    ds_read_b32 (lanes duplicated so readlane indices are literal 0..31).
//  - P3 matvec spread over all 4 P3 waves (2 rows x 32-K each).
// Wave roles (wave w, SIMD = w&3):
//   w<12 (P1): K-chunk c1=w&3, row-group g1=w>>2; rows 128g1+l, 128g1+64+l
//   w>=12 (P3): K-chunk c3=w-12; U_h rows l, 64+l; gates for m3=64*(c3>>1)+l
// 3 phases / 3 LDS-only barriers per step.
// ---------------------------------------------------------------------------
__global__ __launch_bounds__(1024)
__attribute__((amdgpu_waves_per_eu(4, 4)))
void k_seq(float* __restrict__ ws, const float* __restrict__ Wout,
           const float* __restrict__ bout, const float* __restrict__ y,
           float* __restrict__ out) {
    const int t  = threadIdx.x;
    const int l  = t & 63;
    const int w  = t >> 6;               // wave 0..15
    const bool isP1 = (w < 12);
    // P1 mapping
    const int c1 = w & 3;                // K-chunk (32 floats)
    const int g1 = w >> 2;               // row group 0..2
    const int r0 = 128 * g1 + l;         // rows r0 and r0+64
    // P3 mapping
    const int w12 = w - 12;
    const int c3  = w12 & 3;             // K-chunk
    const int q3  = c3 >> 1;             // m-half
    const int m3  = 64 * q3 + l;         // elementwise lane (P3 only)

    __shared__ float part1[4 * 384];     // [chunk][row]
    __shared__ float part3[4 * 128];     // [chunk][row]
    __shared__ float red[HD];            // h*wq products (for next score)
    __shared__ float sS;                 // reduced chain score * SCALE
    __shared__ float h_lds[HD];
    __shared__ float outv[NCLASS];

    // ---- weights: 16 pinned float4 per thread (2 rows x 32-K chunk) ----
    const int woff = isP1 ? (r0 * HD + 32 * c1)
                          : ((384 + l) * HD + 32 * c3);
    const float* wp0 = ws + OFF_W3 + woff;
    const float* wp1 = wp0 + 64 * HD;    // row +64
    float4 A0 = LD4(wp0, 0), A1 = LD4(wp0, 1), A2 = LD4(wp0, 2), A3 = LD4(wp0, 3),
           A4 = LD4(wp0, 4), A5 = LD4(wp0, 5), A6 = LD4(wp0, 6), A7 = LD4(wp0, 7),
           A8 = LD4(wp1, 0), A9 = LD4(wp1, 1), A10 = LD4(wp1, 2), A11 = LD4(wp1, 3),
           A12 = LD4(wp1, 4), A13 = LD4(wp1, 5), A14 = LD4(wp1, 6), A15 = LD4(wp1, 7);
    PIN_ALL();

    // ---- prefetch registers (P3 waves only; element m3) ----
    float pv0 = 0.f, pv1 = 0.f, pv2 = 0.f, paz = 0.f, par = 0.f, pah = 0.f,
          pwq = 0.f, pes = 0.f;
    if (!isP1) {
        pv0 = ws[OFF_PREV + m3];       pv1 = ws[OFF_PREV + 128 + m3];
        pv2 = ws[OFF_PREV + 256 + m3];
        paz = ws[OFF_AZ + m3];         par = ws[OFF_AR + m3];
        pah = ws[OFF_AH + m3];
        pes = ws[OFF_ES];
        pwq = ws[OFF_WQ + HD + m3];    // wq[1], consumed in phase C of step 0
    }
    if (t < HD) {
        h_lds[t] = 0.f;                          // h_{-1} = 0
        red[t]   = (t < 64) ? -1e30f : 0.f;      // step 0: no chain child
    }
    __syncthreads();

    float zreg = 0.f, htvreg = 0.f;

    for (int i = 0; i < NPAR; ++i) {
        const int inext = (i + 1 < NPAR) ? i + 1 : NPAR - 1;
        const int in2   = (i + 2 < NPAR) ? i + 2 : NPAR - 1;

        PIN_ALL();

        // ---- Phase A: P1 matvec. h fetched via ONE per-lane ds_read with
        //      half-wave duplication so readlane indices are literal 0..31.
        //      Wave 12 reduces the chain score concurrently. ----
        if (isP1) {
            const int hx = __float_as_int(h_lds[32 * c1 + (l & 31)]);
            float a0 = 0.f, a1 = 0.f, b0 = 0.f, b1 = 0.f;
            MATVEC2(hx, 0);
            part1[c1 * 384 + r0]      = a0 + a1;
            part1[c1 * 384 + r0 + 64] = b0 + b1;
        } else if (w12 == 0) {
            float s = red[l] + red[l + 64];
#pragma unroll
            for (int o = 32; o > 0; o >>= 1) s += __shfl_down(s, o, 64);
            if (l == 0) sS = s * SCALE;
        }
        BARL();

        // ---- Phase B: P3 waves only: gates for element m3, then 2x32 U_h
        //      matvec on htr (in-lane; readlane base picked by chunk half) ----
        if (!isP1) {
            float e   = expf(sS);
            float vd  = part1[m3]        + part1[384 + m3]
                      + part1[768 + m3]  + part1[1152 + m3];
            float zd  = part1[128 + m3]  + part1[512 + m3]
                      + part1[896 + m3]  + part1[1280 + m3];
            float rd  = part1[256 + m3]  + part1[640 + m3]
                      + part1[1024 + m3] + part1[1408 + m3];
            float inv = 1.f / (pes + e);
            float htv = (pv0 + e * vd) * inv;
            float z   = 1.f / (1.f + expf(-(paz + (pv1 + e * zd) * inv)));
            float rr  = 1.f / (1.f + expf(-(par + (pv2 + e * rd) * inv)));
            float htr = htv * rr;
            zreg = z; htvreg = htv;
            const int xh = __float_as_int(htr);
            float a0 = 0.f, a1 = 0.f, b0 = 0.f, b1 = 0.f;
            if ((c3 & 1) == 0) { MATVEC2(xh, 0); } else { MATVEC2(xh, 32); }
            part3[c3 * 128 + l]      = a0 + a1;
            part3[c3 * 128 + l + 64] = b0 + b1;
        }
        BARL();

        // ---- Phase C: P3 waves: finalize h[m3]; publish h + score products;
        //      refill prefetches (fire-and-forget) ----
        if (!isP1) {
            float u  = part3[m3]       + part3[128 + m3]
                     + part3[256 + m3] + part3[384 + m3];
            float c  = tanhf(pah + u);
            float hv = zreg * htvreg + (1.f - zreg) * c;
            if ((w12 & 1) == 0) {       // one wave per half: w12=0 (q0), 2 (q1)
                h_lds[m3] = hv;
                red[m3]   = hv * pwq;   // <h_i, wq_{i+1}> products
            }
            pv0 = ws[OFF_PREV + inext * 384 + m3];
            pv1 = ws[OFF_PREV + inext * 384 + 128 + m3];
            pv2 = ws[OFF_PREV + inext * 384 + 256 + m3];
            paz = ws[OFF_AZ + inext * HD + m3];
            par = ws[OFF_AR + inext * HD + m3];
            pah = ws[OFF_AH + inext * HD + m3];
            pes = ws[OFF_ES + inext];
            pwq = ws[OFF_WQ + in2 * HD + m3];
        }
        BARL();
    }

    // ---- output head (h_lds holds h_{NPAR-1}) ----
    if (t < NCLASS) {
        float acc = bout[t];
#pragma unroll 4
        for (int k = 0; k < HD; ++k) acc += Wout[(size_t)t * HD + k] * h_lds[k];
        outv[t] = acc;
    }
    __syncthreads();
    if (t == 0) {
        float mx = fmaxf(fmaxf(outv[0], outv[1]), fmaxf(outv[2], outv[3]));
        float e0 = expf(outv[0] - mx), e1 = expf(outv[1] - mx);
        float e2 = expf(outv[2] - mx), e3 = expf(outv[3] - mx);
        float inv = 1.f / (e0 + e1 + e2 + e3);
        float p0 = e0 * inv, p1 = e1 * inv, p2 = e2 * inv, p3 = e3 * inv;
        out[0] = p0; out[1] = p1; out[2] = p2; out[3] = p3;
        float d0 = y[0] - p0, d1 = y[1] - p1, d2 = y[2] - p2, d3 = y[3] - p3;
        out[4] = d0 * d0 + d1 * d1 + d2 * d2 + d3 * d3;
    }
}

// ---------------------------------------------------------------------------
extern "C" void kernel_launch(void* const* d_in, const int* in_sizes, int n_in,
                              void* d_out, int out_size, void* d_ws, size_t ws_size,
                              hipStream_t stream) {
    const float* x_word  = (const float*)d_in[0];
    const int*   x_index = (const int*)d_in[1];
    const int*   tree    = (const int*)d_in[2];
    const float* y       = (const float*)d_in[3];
    const float* E_bu    = (const float*)d_in[4];
    const float* WQ      = (const float*)d_in[5];
    const float* WK      = (const float*)d_in[6];
    const float* WV      = (const float*)d_in[7];
    const float* W_z     = (const float*)d_in[8];
    const float* U_z     = (const float*)d_in[9];
    const float* b_z     = (const float*)d_in[10];
    const float* W_r     = (const float*)d_in[11];
    const float* U_r     = (const float*)d_in[12];
    const float* b_r     = (const float*)d_in[13];
    const float* W_h     = (const float*)d_in[14];
    const float* U_h     = (const float*)d_in[15];
    const float* b_h     = (const float*)d_in[16];
    const float* W_out   = (const float*)d_in[17];
    const float* b_out   = (const float*)d_in[18];

    float* ws      = (float*)d_ws;
    float* xe      = ws + OFF_XE;
    float* node_h  = ws + OFF_NODE;
    float* w3      = ws + OFF_W3;
    float* wq      = ws + OFF_WQ;
    float* az      = ws + OFF_AZ;
    float* ar      = ws + OFF_AR;
    float* ah      = ws + OFF_AH;
    float* preVexp = ws + OFF_PREV;
    float* expsum  = ws + OFF_ES;
    float* ET      = ws + OFF_ET;

    bool use_transpose = ws_size >= WS_END * sizeof(float);

    if (use_transpose) {
        dim3 tg(VOCABN / 32, HD / 32), tb(32, 8);
        k_transpose<<<tg, tb, 0, stream>>>(E_bu, ET);
        k_xe_t<<<NNODE, HD, 0, stream>>>(x_word, x_index, ET, xe);
    } else {
        k_xe<<<NNODE, HD, 0, stream>>>(x_word, x_index, E_bu, xe);
    }
    k_leaf<<<NLEAF, HD, 0, stream>>>(xe, W_z, b_z, W_h, b_h, node_h);
    k_fuse<<<512, HD, 0, stream>>>(WV, U_z, U_r, U_h, w3);
    k_ppre<<<NPAR, HD, 0, stream>>>(xe, WQ, WK, W_z, b_z, W_r, b_r, W_h, b_h,
                                    wq, az, ar, ah);
    k_chpre<<<NPAR, HD, 0, stream>>>(tree, node_h, w3, wq, preVexp, expsum);
    k_seq<<<1, 1024, 0, stream>>>(ws, W_out, b_out, y, (float*)d_out);
}